// Round 1
// 6593.752 us; speedup vs baseline: 1.1528x; 1.1528x over previous
//
#include <hip/hip_runtime.h>
#include <hip/hip_bf16.h>

// Leaky RNN h_{t+1} = 0.9 h_t + 0.1 (h_t A^T + x_t), NS=32, T=2048, N=1024.
// Chunked warm-up: 256 workgroups, chunk c owns outputs t in [8c, 8c+8), warm
// start W=96 steps early from h=0 (error <= 0.94^96 * |h| ~ 6e-4), exact from
// h0 when window reaches t=0.
// Round 1 changes vs 7.6ms baseline (latency-bound: occ 22%, MfmaUtil 12%):
//  - 1024 threads / 16 waves: per-thread state halves -> <=128 VGPR ->
//    4 waves/SIMD (2x TLP) and batched B-fragment loads.
//  - nontemporal inp/out: keep 2MB Bp resident in each XCD L2 (inp streamed
//    4MB/step/XCD was evicting it to L3; Bp re-read = 9.3 TB/s ceiling).
//  - WARM 128->96: steps 136->104.
//  - XCD swizzle: neighboring chunks (inp windows overlap by 8 steps) share an
//    XCD L2 -> inp fetched ~once per XCD instead of per CU.

#define NSAMP 32
#define TSTEPS 2048
#define NDIM 1024
#define CHUNK_L 8
#define WARM 96
#define NCHUNK (TSTEPS / CHUNK_L)   // 256
#define HS_STRIDE 1544              // bf16 elems/row; (3088B/4)%32=4 -> 2-way (free) on b128 reads

typedef __attribute__((ext_vector_type(8))) short short8;
typedef __attribute__((ext_vector_type(4))) float floatx4;

// Bp[kt][n][kk] = bf16(A[n][kt*32+kk]) : B-operand (A^T) packed so each lane's
// 8-elem fragment (n = lane&15, k = kt*32 + quad*8 + j) is 16B contiguous.
__global__ __launch_bounds__(256)
void prep_A_kernel(const float* __restrict__ A, __hip_bfloat16* __restrict__ Bp) {
    int idx = blockIdx.x * 256 + threadIdx.x;   // idx = n*1024 + k
    int k  = idx & (NDIM - 1);
    int n  = idx >> 10;
    int kt = k >> 5, kk = k & 31;
    Bp[((kt << 10) + n) * 32 + kk] = __float2bfloat16(A[idx]);
}

__global__ __launch_bounds__(1024, 1)
void rnn_chunk_kernel(const float* __restrict__ inp,
                      const float* __restrict__ h0,
                      const __hip_bfloat16* __restrict__ Bp,
                      float* __restrict__ out) {
    __shared__ __hip_bfloat16 Hs[NSAMP * HS_STRIDE];

    // XCD swizzle: blocks dispatch round-robin over 8 XCDs; map so XCD x hosts
    // chunks [32x, 32x+32) -> overlapping inp windows share one L2.
    const int c    = ((blockIdx.x & 7) << 5) | (blockIdx.x >> 3);
    const int tid  = threadIdx.x;
    const int lane = tid & 63;
    const int wave = tid >> 6;       // 0..15, owns n-tiles wave*4 .. wave*4+3
    const int q    = lane >> 4;      // quad
    const int m16  = lane & 15;

    const int out_lo  = c * CHUNK_L;
    const int out_hi  = out_lo + CHUNK_L;
    const int t_start = (out_lo > WARM) ? (out_lo - WARM) : 0;

    // fragment element (mt, j, r): s = mt*16 + q*4 + r ; n = (wave*4+j)*16 + m16
    float hreg[2][4][4];   // fp32 master state, persistent across steps (32 VGPR)

    #pragma unroll
    for (int mt = 0; mt < 2; ++mt)
    #pragma unroll
    for (int j = 0; j < 4; ++j) {
        const int n = (wave * 4 + j) * 16 + m16;
        #pragma unroll
        for (int r = 0; r < 4; ++r) {
            const int s = mt * 16 + q * 4 + r;
            const float h = (t_start == 0) ? h0[s * NDIM + n] : 0.0f;
            hreg[mt][j][r] = h;
            Hs[s * HS_STRIDE + n] = __float2bfloat16(h);
            if (c == 0) out[((size_t)s * TSTEPS) * NDIM + n] = h;   // t=0 output
        }
    }
    __syncthreads();

    for (int t = t_start + 1; t < out_hi; ++t) {
        floatx4 acc[2][4] = {};

        // acc = H_bf16 @ A^T_bf16 ; H from LDS (A-frag), A^T streamed from L2 (B-frag)
        for (int kt = 0; kt < 32; ++kt) {
            const short8 a0 = *(const short8*)&Hs[(m16     ) * HS_STRIDE + kt * 32 + q * 8];
            const short8 a1 = *(const short8*)&Hs[(m16 + 16) * HS_STRIDE + kt * 32 + q * 8];
            short8 b[4];
            #pragma unroll
            for (int j = 0; j < 4; ++j)
                b[j] = *(const short8*)&Bp[(size_t)(kt * NDIM + (wave * 4 + j) * 16 + m16) * 32 + q * 8];
            #pragma unroll
            for (int j = 0; j < 4; ++j) {
                acc[0][j] = __builtin_amdgcn_mfma_f32_16x16x32_bf16(a0, b[j], acc[0][j], 0, 0, 0);
                acc[1][j] = __builtin_amdgcn_mfma_f32_16x16x32_bf16(a1, b[j], acc[1][j], 0, 0, 0);
            }
        }

        __syncthreads();   // everyone done reading Hs(h_{t-1})

        const bool emit = (t >= out_lo);
        #pragma unroll
        for (int mt = 0; mt < 2; ++mt)
        #pragma unroll
        for (int j = 0; j < 4; ++j) {
            const int n = (wave * 4 + j) * 16 + m16;
            #pragma unroll
            for (int r = 0; r < 4; ++r) {
                const int s = mt * 16 + q * 4 + r;
                const float x = __builtin_nontemporal_load(&inp[((size_t)s * TSTEPS + (t - 1)) * NDIM + n]);
                const float h = 0.9f * hreg[mt][j][r] + 0.1f * (acc[mt][j][r] + x);
                hreg[mt][j][r] = h;
                Hs[s * HS_STRIDE + n] = __float2bfloat16(h);
                if (emit) __builtin_nontemporal_store(h, &out[((size_t)s * TSTEPS + t) * NDIM + n]);
            }
        }
        __syncthreads();   // Hs(h_t) visible before next GEMM
    }
}

extern "C" void kernel_launch(void* const* d_in, const int* in_sizes, int n_in,
                              void* d_out, int out_size, void* d_ws, size_t ws_size,
                              hipStream_t stream) {
    const float* inp = (const float*)d_in[0];   // [32, 2048, 1024]
    const float* A   = (const float*)d_in[1];   // [1024, 1024]
    const float* h0  = (const float*)d_in[2];   // [32, 1024]
    float* out = (float*)d_out;                 // [32, 2048, 1024]
    __hip_bfloat16* Bp = (__hip_bfloat16*)d_ws; // 2 MB packed bf16 A^T

    hipLaunchKernelGGL(prep_A_kernel, dim3((NDIM * NDIM) / 256), dim3(256), 0, stream, A, Bp);
    hipLaunchKernelGGL(rnn_chunk_kernel, dim3(NCHUNK), dim3(1024), 0, stream, inp, h0, Bp, out);
}